// Round 7
// baseline (347.702 us; speedup 1.0000x reference)
//
#include <hip/hip_runtime.h>
#include <hip/hip_bf16.h>

// AdaptiveGraphConvolution on MI355X — round 9.
// N=64, C=64, T=300, V=25, S=3 subsets, IC=16, O=64.
//
// Round-8 post-mortem: k3 fixed (out of top-5). k1 back on top at 93 us
// with NOTHING visible: VALU 12.8%, MFMA 3.8%, HBM 11%, Occ 19% -> ~85%
// stall. Cycle audit of visible work says ~6 us/block-round; the only
// uncounted op is the tail's 1.56M device-scope atomicAdd onto 120K
// floats (~210 serialized RMWs per cache line at the coherent point;
// per-XCD L2s aren't coherent so these RMW at the fabric/MALL).
// Round-9: REMOVE the cross-block atomic reduction.
//  * k1 tail: plain global stores of the 3x625 partial M into
//    Mp[i][n][chunk][625] (12 MB, zero contention, no pre-zeroing).
//  * k2: sums the 25 chunk partials per (i,n) (15,625 coalesced f32
//    loads/block) before softmax.
//  * k0: Mb zeroing deleted (nothing to accumulate into).
// Everything else byte-identical to round 8.
// Workspace: Mp 12,000,000 B | atT 393,216 B | gwb 24,576 B (~12.4 MB).

#define NB 64
#define CB 64
#define TB 300
#define VB 25
#define XTOT (NB * CB * TB * VB)

typedef unsigned int uint32;
typedef unsigned short ushort16;
typedef __attribute__((ext_vector_type(8))) short short8;
typedef __attribute__((ext_vector_type(4))) float f32x4;
typedef __attribute__((ext_vector_type(16))) float f32x16;

__device__ __forceinline__ ushort16 f2bf(float f) {
    __hip_bfloat16 h = __float2bfloat16(f);
    ushort16 u;
    __builtin_memcpy(&u, &h, sizeof(u));
    return u;
}
__device__ __forceinline__ float bf2f(ushort16 h) {
    return __uint_as_float(((uint32)h) << 16);
}
__device__ __forceinline__ uint32 packbf2(float a, float b) {
    return (uint32)f2bf(a) | ((uint32)f2bf(b) << 16);
}

// ---------------------------------------------------------------- kernel 0
// one-time weight prep. grid 48 x 256.
//   idx <  6144: W bf16, layout [kb8][r][8]
//   idx < 12288: g_w -> gwb bf16 pairs (k3 A-operand layout)
__global__ __launch_bounds__(256) void k0_prep(
    const float* __restrict__ a_w, const float* __restrict__ b_w,
    const float* __restrict__ g_w,
    ushort16* __restrict__ wb2, uint32* __restrict__ gwb)
{
    int idx = blockIdx.x * 256 + threadIdx.x;
    if (idx < 6144) {
        int kb = idx / 768, rem = idx % 768;
        int r = rem >> 3, ci = rem & 7;
        int c = kb * 8 + ci;
        float v = (r < 48) ? a_w[r * 64 + c] : b_w[(r - 48) * 64 + c];
        wb2[idx] = f2bf(v);
    } else if (idx < 12288) {
        int j = idx - 6144;
        int o = j / 96, kp = j % 96;
        int k0 = 2 * kp, i = k0 >> 6, c = k0 & 63;
        float2 lh = *(const float2*)(g_w + (i * 64 + o) * 64 + c);
        gwb[j] = packbf2(lh.x, lh.y);
    }
}

// ---------------------------------------------------------------- kernel 1
// grid 1600 = 64 n * 25 chunks (12 t), 256 thr = 4 waves, 4 blocks/CU
__global__ __launch_bounds__(256) void k1_attn_logits_mfma(
    const float* __restrict__ x, const ushort16* __restrict__ wb2,
    const float* __restrict__ a_b, const float* __restrict__ b_b,
    float* __restrict__ Mp)
{
    // pool: xT[126 rows][64] + abT[192 rows][64]. 40704 B -> 4 blocks/CU.
    __shared__ ushort16 pool[20352];
    ushort16* xT  = pool;
    ushort16* abT = pool + 126 * 64;

    const int tid   = threadIdx.x;
    const int n     = blockIdx.x / 25;
    const int chunk = blockIdx.x % 25;
    const float* xn = x + n * (CB * TB * VB);

    // bias stash: f32 in abT rows 31/63/95 (phase-B reads of rows v>=25
    // produce discarded outputs; phase-A writes only touch v<25).
    if (tid < 96) {
        float v = (tid < 48) ? a_b[tid] : b_b[tid - 48];
        ((float*)(abT + (31 + (tid >> 5) * 32) * 64))[tid & 31] = v;
    }

    const int w    = tid >> 6;
    const int lane = tid & 63;
    const int hi   = lane >> 5;
    const int v32  = lane & 31;

    const float* xb0 = xn + chunk * 12 * 25;

    // phase-A hoists: wave w owns col-tile ct=w
    const int tv     = w * 32 + v32;
    const bool avalid = tv < 100;
    const int tl = tv / 25;
    const int vv = tv - tl * 25;

    f32x16 accB;
    #pragma unroll
    for (int r = 0; r < 16; ++r) accB[r] = 0.f;

    for (int s = 0; s < 3; ++s) {
        __syncthreads();   // phase A/B of s-1 done with xT/abT
        // ---- stage x^T sub-chunk: load + cvt + swizzled LDS write.
        // row tv = 4j+e, swizzle block = ((c>>3) + 5j + e) & 7.
        const float* xs0 = xb0 + s * 100;
        #pragma unroll
        for (int k = 0; k < 7; ++k) {
            int idx = tid + k * 256;
            if (idx < 1600) {
                int c = idx / 25, j = idx - c * 25;
                float4 v4 = *(const float4*)(xs0 + c * 7500 + j * 4);
                int sb   = ((c >> 3) + 5 * j) & 7;
                int base = (4 * j) * 64 + (c & 7);
                xT[base +   0 + (((sb + 0) & 7) << 3)] = f2bf(v4.x);
                xT[base +  64 + (((sb + 1) & 7) << 3)] = f2bf(v4.y);
                xT[base + 128 + (((sb + 2) & 7) << 3)] = f2bf(v4.z);
                xT[base + 192 + (((sb + 3) & 7) << 3)] = f2bf(v4.w);
            }
        }
        __syncthreads();
        // ---- phase A: ab = W @ x on 32x32x16; 3 rt tiles, ct = w
        #pragma unroll
        for (int rt = 0; rt < 3; ++rt) {
            f32x16 d;
            #pragma unroll
            for (int r = 0; r < 16; ++r) d[r] = 0.f;
            #pragma unroll
            for (int k16 = 0; k16 < 4; ++k16) {
                int kb = k16 * 2 + hi;
                short8 af = *(const short8*)(wb2 + (kb * 96 + rt * 32 + v32) * 8);
                short8 bf = *(const short8*)&xT[tv * 64 +
                                                (((kb + tv + (tv >> 2)) & 7) << 3)];
                d = __builtin_amdgcn_mfma_f32_32x32x16_bf16(af, bf, d, 0, 0, 0);
            }
            if (avalid) {
                #pragma unroll
                for (int a = 0; a < 4; ++a) {
                    int rowoff = 8 * a + 4 * hi;            // D row within 32
                    int g   = rt * 2 + (rowoff >> 4);       // abT group
                    int icb = rowoff & 15;
                    float4 bq = *(const float4*)(
                        (const float*)(abT + (31 + rt * 32) * 64) + rowoff);
                    int kbw = tl * 2 + (icb >> 3);
                    uint32* dst = (uint32*)&abT[(g * 32 + vv) * 64 +
                                                (((kbw + vv) & 7) << 3) + (icb & 7)];
                    dst[0] = packbf2(d[4 * a + 0] + bq.x, d[4 * a + 1] + bq.y);
                    dst[1] = packbf2(d[4 * a + 2] + bq.z, d[4 * a + 3] + bq.w);
                }
            }
        }
        __syncthreads();
        // ---- phase B: wave w (<3) owns subset i=w, all 4 local t
        if (w < 3) {
            #pragma unroll
            for (int tl2 = 0; tl2 < 4; ++tl2) {
                int kb = tl2 * 2 + hi;
                short8 af = *(const short8*)&abT[(w * 32 + v32) * 64 +
                                                 (((kb + v32) & 7) << 3)];
                short8 bf = *(const short8*)&abT[((3 + w) * 32 + v32) * 64 +
                                                 (((kb + v32) & 7) << 3)];
                accB = __builtin_amdgcn_mfma_f32_32x32x16_bf16(af, bf, accB, 0, 0, 0);
            }
        }
    }

    // ---- tail: plain stores of the partial M_i into this block's
    // private slice Mp[i][n][chunk][625] (no contention, no atomics)
    if (w < 3 && v32 < 25) {
        const float inv = 1.0f / 4800.0f;
        float* dst = Mp + ((w * NB + n) * 25 + chunk) * 625;
        #pragma unroll
        for (int r = 0; r < 16; ++r) {
            int row = (r & 3) + 8 * (r >> 2) + 4 * hi;   // m74/m101 C-layout
            if (row < 25)
                dst[row * 25 + v32] = accB[r] * inv;
        }
    }
}

// ---------------------------------------------------------------- kernel 2
// 192 blocks = (i,n); sum 25 chunk-partials, softmax over v1 + A_tot
// -> atT bf16 [i][n][v2][v1 pad32]
__global__ __launch_bounds__(128) void k2_softmax(
    const float* __restrict__ Mp, const float* __restrict__ A,
    const float* __restrict__ GA, uint32* __restrict__ atT)
{
    __shared__ float Ms[640];
    const int b   = blockIdx.x;
    const int tid = threadIdx.x;
    const int i = b >> 6, n = b & 63;
    const float* src = Mp + (size_t)b * 25 * 625;   // [i][n] slice, contiguous
    for (int idx = tid; idx < 625; idx += 128) {
        float ssum = 0.f;
        #pragma unroll 5
        for (int ch = 0; ch < 25; ++ch) ssum += src[ch * 625 + idx];
        Ms[idx] = ssum;
    }
    __syncthreads();
    if (tid < 25) {
        const int v2 = tid;
        float e[25], mx = -1e30f;
        #pragma unroll
        for (int v1 = 0; v1 < 25; ++v1) {
            e[v1] = Ms[v1 * 25 + v2];
            mx = fmaxf(mx, e[v1]);
        }
        float s = 0.f;
        #pragma unroll
        for (int v1 = 0; v1 < 25; ++v1) { e[v1] = __expf(e[v1] - mx); s += e[v1]; }
        float invs = 1.0f / s;
        const float* acol = A + i * 625 + v2;
        const float* gcol = GA + i * 625 + v2;
        float wv[25];
        #pragma unroll
        for (int v1 = 0; v1 < 25; ++v1)
            wv[v1] = e[v1] * invs + acol[v1 * 25] + gcol[v1 * 25];
        uint32* row = atT + ((i * 64 + n) * 32 + v2) * 16;
        #pragma unroll
        for (int p = 0; p < 12; ++p) row[p] = packbf2(wv[2 * p], wv[2 * p + 1]);
        row[12] = (uint32)f2bf(wv[24]);
        row[13] = 0u; row[14] = 0u; row[15] = 0u;
    }
}

// ---------------------------------------------------------------- kernel 3
// Stage-less MFMA. grid 3840 = 64 n * 60 chunks of 5 t; 256 thr = 4 waves.
// LDS: xa 18432 + bsc/bsh 512 = 18944 B.
__global__ __launch_bounds__(256) void k3_out(
    const float* __restrict__ x, const uint32* __restrict__ atT,
    const ushort16* __restrict__ gwb, const float* __restrict__ g_b,
    const float* __restrict__ bn_g, const float* __restrict__ bn_b,
    const float* __restrict__ bn_m, const float* __restrict__ bn_v,
    float* __restrict__ out)
{
    __shared__ uint32 xa[128 * 36];     // [col=(t,v2) pad128][c: 72 bf16 as 36 u32]
    __shared__ float  bsc[64], bsh[64];

    const int tid = threadIdx.x;
    const int n  = blockIdx.x / 60;
    const int t0 = (blockIdx.x % 60) * 5;

    // BN scale/shift prefold (h = acc*sc + sh + x)
    if (tid < 64) {
        float sc = bn_g[tid] * rsqrtf(bn_v[tid] + 1e-5f);
        bsc[tid] = sc;
        bsh[tid] = (g_b[tid] + g_b[64 + tid] + g_b[128 + tid] - bn_m[tid]) * sc
                   + bn_b[tid];
    }
    // zero xa pad rows (cols 125..127)
    for (int idx = tid; idx < 108; idx += 256)
        xa[(125 + idx / 36) * 36 + idx % 36] = 0u;

    const int w    = tid >> 6;      // wave id = o-tile (main) = c-tile (xa)
    const int lane = tid & 63;
    const int l15  = lane & 15;
    const int q    = lane >> 4;

    // preload A-frags of gw (all 6 K-steps: k = i*64 + s*32)
    short8 gf[6];
    #pragma unroll
    for (int s = 0; s < 6; ++s)
        gf[s] = *(const short8*)(gwb + ((w * 16 + l15) * 192 + s * 32 + q * 8));

    // A-frags of x direct from global: lane (q,l15) of wave w holds
    // c = w*16+l15, k = v1 in [q*8, q*8+8). v1 >= 25 reads the next t-row
    // (garbage but finite, in-bounds via clamp) and meets B's zero pad.
    const int c    = w * 16 + l15;
    const int rowf = (n * 64 + c) * 7500 + t0 * 25;
    short8 axf[5];
    #pragma unroll
    for (int t = 0; t < 5; ++t) {
        int fi = rowf + t * 25 + q * 8;
        fi = fi < (XTOT - 8) ? fi : (XTOT - 8);
        const float* p = x + fi;
        union { short8 s; uint32 u[4]; } fr;
        fr.u[0] = packbf2(p[0], p[1]);
        fr.u[1] = packbf2(p[2], p[3]);
        fr.u[2] = packbf2(p[4], p[5]);
        fr.u[3] = packbf2(p[6], p[7]);
        axf[t] = fr.s;
    }

    f32x4 acc[8];
    #pragma unroll
    for (int ct = 0; ct < 8; ++ct) acc[ct] = (f32x4){0.f, 0.f, 0.f, 0.f};
    const f32x4 zf = (f32x4){0.f, 0.f, 0.f, 0.f};

    __syncthreads();

    for (int i = 0; i < 3; ++i) {
        if (i) __syncthreads();   // previous xa fully consumed
        // B-frags for this i straight from global atT (16B-aligned, L2-hot)
        const ushort16* ap = (const ushort16*)atT + ((i * 64 + n) * 32) * 32;
        short8 bt0 = *(const short8*)(ap + l15 * 32 + q * 8);
        short8 bt1 = *(const short8*)(ap + (16 + l15) * 32 + q * 8);
        // ---- xa-phase: this wave produces c-rows [w*16, w*16+16)
        #pragma unroll
        for (int t = 0; t < 5; ++t) {
            #pragma unroll
            for (int vt = 0; vt < 2; ++vt) {
                f32x4 d = __builtin_amdgcn_mfma_f32_16x16x32_bf16(
                    axf[t], vt ? bt1 : bt0, zf, 0, 0, 0);
                int v2 = vt * 16 + l15;
                if (v2 < 25) {
                    int col = t * 25 + v2;
                    int c0  = w * 16 + q * 4;
                    xa[col * 36 + (c0 >> 1)]     = packbf2(d[0], d[1]);
                    xa[col * 36 + (c0 >> 1) + 1] = packbf2(d[2], d[3]);
                }
            }
        }
        __syncthreads();
        // ---- main GEMM: acc[o,col] += gw_i[o,c] * xa[c,col]
        #pragma unroll
        for (int ct = 0; ct < 8; ++ct) {
            #pragma unroll
            for (int s = 0; s < 2; ++s) {
                short8 bfrag = *(const short8*)((const ushort16*)xa +
                                                (ct * 16 + l15) * 72 + s * 32 + q * 8);
                acc[ct] = __builtin_amdgcn_mfma_f32_16x16x32_bf16(
                    gf[i * 2 + s], bfrag, acc[ct], 0, 0, 0);
            }
        }
    }

    // ---- epilogue: BN + residual (f32 x from global, same offsets as out)
    const int o0 = w * 16 + q * 4;
    #pragma unroll
    for (int ct = 0; ct < 8; ++ct) {
        int col = ct * 16 + l15;
        if (col < 125) {
            int off = (n * 64 + o0) * 7500 + t0 * 25 + col;
            float* ob = out + off;
            const float* xb = x + off;
            #pragma unroll
            for (int r = 0; r < 4; ++r) {
                float h = acc[ct][r] * bsc[o0 + r] + bsh[o0 + r] + xb[r * 7500];
                ob[r * 7500] = fmaxf(h, 0.f);
            }
        }
    }
}

// ---------------------------------------------------------------- launch
extern "C" void kernel_launch(void* const* d_in, const int* in_sizes, int n_in,
                              void* d_out, int out_size, void* d_ws, size_t ws_size,
                              hipStream_t stream) {
    const float* x    = (const float*)d_in[0];
    const float* A    = (const float*)d_in[1];
    const float* GA   = (const float*)d_in[2];
    const float* g_w  = (const float*)d_in[3];
    const float* g_b  = (const float*)d_in[4];
    const float* a_w  = (const float*)d_in[5];
    const float* a_b  = (const float*)d_in[6];
    const float* b_w  = (const float*)d_in[7];
    const float* b_b  = (const float*)d_in[8];
    const float* bn_g = (const float*)d_in[9];
    const float* bn_b = (const float*)d_in[10];
    const float* bn_m = (const float*)d_in[11];
    const float* bn_v = (const float*)d_in[12];
    float* out = (float*)d_out;

    // ws: Mp f32 [3][64][25][625] (12,000,000 B) | atT bf16 (393,216 B)
    //     | gwb (24,576 B). wb2 (12,288 B) OVERLAPS the start of atT:
    // k0 writes wb2 -> k1 reads wb2 -> k2 overwrites region with atT ->
    // k3 reads atT. Stream-serial. No memset needed (Mp fully overwritten).
    float*    Mp  = (float*)d_ws;
    uint32*   atT = (uint32*)((char*)d_ws + 12000000);
    ushort16* wb2 = (ushort16*)((char*)d_ws + 12000000);
    uint32*   gwb = (uint32*)((char*)d_ws + 12000000 + 393216);

    k0_prep<<<dim3(48), dim3(256), 0, stream>>>(a_w, b_w, g_w, wb2, gwb);
    k1_attn_logits_mfma<<<dim3(1600), dim3(256), 0, stream>>>(x, wb2, a_b, b_b, Mp);
    k2_softmax<<<dim3(192), dim3(128), 0, stream>>>(Mp, A, GA, atT);
    k3_out<<<dim3(3840), dim3(256), 0, stream>>>(x, atT, (const ushort16*)gwb,
                                                 g_b, bn_g, bn_b, bn_m, bn_v, out);
}

// Round 9
// 327.409 us; speedup vs baseline: 1.0620x; 1.0620x over previous
//
#include <hip/hip_runtime.h>
#include <hip/hip_bf16.h>

// AdaptiveGraphConvolution on MI355X — round 11.
// N=64, C=64, T=300, V=25, S=3 subsets, IC=16, O=64.
//
// Round-10 post-mortem: correctness FAIL from macro hygiene, not the
// pipeline. ST_LOADW's inner `float4 v4 = PV;` with call-site arg `v4`
// expanded to `float4 v4 = v4;` (self-init garbage) in the St(0)
// prologue -> sub-chunk 0 staged garbage in every block. Fix: hygienic
// macro locals (pv_/idx_/c_/j_/sb_/base_). Pipeline re-audited clean:
// merged region touches disjoint LDS (xT writes vs abT reads).
// Round-11 = round-10 design, fixed:
//  * k1 software-pipeline: St(0); bar; { A(s); bar; [St(s+1) || B(s)];
//    bar }x2; A(2); bar; B(2). 6 barriers (was 9); staging HBM latency
//    hides under B's MFMAs; halves split caps in-flight float4 at 4
//    (peak VGPR ~50 < 64, round-5/6 spill lesson).
//  * k2: Mp chunk stride 640 (16B-aligned); float4 chunk-sum, 256 thr.
// k0/k3 unchanged from round 9 (last passing).
// Workspace: Mp 12,288,000 B | atT 393,216 B | gwb 24,576 B (ws ~490 MB
// per round-7 fill counters -> fits).

#define NB 64
#define CB 64
#define TB 300
#define VB 25
#define XTOT (NB * CB * TB * VB)

typedef unsigned int uint32;
typedef unsigned short ushort16;
typedef __attribute__((ext_vector_type(8))) short short8;
typedef __attribute__((ext_vector_type(4))) float f32x4;
typedef __attribute__((ext_vector_type(16))) float f32x16;

__device__ __forceinline__ ushort16 f2bf(float f) {
    __hip_bfloat16 h = __float2bfloat16(f);
    ushort16 u;
    __builtin_memcpy(&u, &h, sizeof(u));
    return u;
}
__device__ __forceinline__ float bf2f(ushort16 h) {
    return __uint_as_float(((uint32)h) << 16);
}
__device__ __forceinline__ uint32 packbf2(float a, float b) {
    return (uint32)f2bf(a) | ((uint32)f2bf(b) << 16);
}

// ---------------------------------------------------------------- kernel 0
// one-time weight prep. grid 48 x 256.
//   idx <  6144: W bf16, layout [kb8][r][8]
//   idx < 12288: g_w -> gwb bf16 pairs (k3 A-operand layout)
__global__ __launch_bounds__(256) void k0_prep(
    const float* __restrict__ a_w, const float* __restrict__ b_w,
    const float* __restrict__ g_w,
    ushort16* __restrict__ wb2, uint32* __restrict__ gwb)
{
    int idx = blockIdx.x * 256 + threadIdx.x;
    if (idx < 6144) {
        int kb = idx / 768, rem = idx % 768;
        int r = rem >> 3, ci = rem & 7;
        int c = kb * 8 + ci;
        float v = (r < 48) ? a_w[r * 64 + c] : b_w[(r - 48) * 64 + c];
        wb2[idx] = f2bf(v);
    } else if (idx < 12288) {
        int j = idx - 6144;
        int o = j / 96, kp = j % 96;
        int k0 = 2 * kp, i = k0 >> 6, c = k0 & 63;
        float2 lh = *(const float2*)(g_w + (i * 64 + o) * 64 + c);
        gwb[j] = packbf2(lh.x, lh.y);
    }
}

// ---------------------------------------------------------------- kernel 1
// grid 1600 = 64 n * 25 chunks (12 t), 256 thr = 4 waves, 4 blocks/CU
// Pipeline: St(0); bar; { A(s); bar; [St(s+1) || B(s)]; bar }x2; A(2);
// bar; B(2); tail.  6 barriers (was 9).
__global__ __launch_bounds__(256) void k1_attn_logits_mfma(
    const float* __restrict__ x, const ushort16* __restrict__ wb2,
    const float* __restrict__ a_b, const float* __restrict__ b_b,
    float* __restrict__ Mp)
{
    // pool: xT[126 rows][64] + abT[192 rows][64]. 40704 B -> 4 blocks/CU.
    __shared__ ushort16 pool[20352];
    ushort16* xT  = pool;
    ushort16* abT = pool + 126 * 64;

    const int tid   = threadIdx.x;
    const int n     = blockIdx.x / 25;
    const int chunk = blockIdx.x % 25;
    const float* xn = x + n * (CB * TB * VB);

    // bias stash: f32 in abT rows 31/63/95 (phase-B reads of rows v>=25
    // produce discarded outputs; phase-A writes only touch v<25).
    if (tid < 96) {
        float v = (tid < 48) ? a_b[tid] : b_b[tid - 48];
        ((float*)(abT + (31 + (tid >> 5) * 32) * 64))[tid & 31] = v;
    }

    const int w    = tid >> 6;
    const int lane = tid & 63;
    const int hi   = lane >> 5;
    const int v32  = lane & 31;

    const float* xb0 = xn + chunk * 12 * 25;

    // phase-A hoists: wave w owns col-tile ct=w
    const int tv     = w * 32 + v32;
    const bool avalid = tv < 100;
    const int tl = tv / 25;
    const int vv = tv - tl * 25;

    f32x16 accB;
    #pragma unroll
    for (int r = 0; r < 16; ++r) accB[r] = 0.f;

    // staging unit: idx = tid + k*256; k<6 always valid, k=6 iff tid<64.
    // row tv = 4j+e, swizzle block = ((c>>3) + 5j + e) & 7.
    // NOTE: hygienic locals (pv_/idx_/...) — round-10 failed on
    // `float4 v4 = PV;` expanding to self-init when PV was named v4.
#define ST_LOADW(PV, K)                                                 \
    {                                                                   \
        int idx_ = tid + (K) * 256;                                     \
        int c_ = idx_ / 25, j_ = idx_ - c_ * 25;                        \
        float4 pv_ = (PV);                                              \
        int sb_   = ((c_ >> 3) + 5 * j_) & 7;                           \
        int base_ = (4 * j_) * 64 + (c_ & 7);                           \
        xT[base_ +   0 + (((sb_ + 0) & 7) << 3)] = f2bf(pv_.x);         \
        xT[base_ +  64 + (((sb_ + 1) & 7) << 3)] = f2bf(pv_.y);         \
        xT[base_ + 128 + (((sb_ + 2) & 7) << 3)] = f2bf(pv_.z);         \
        xT[base_ + 192 + (((sb_ + 3) & 7) << 3)] = f2bf(pv_.w);         \
    }
#define ST_LOAD(SRC, K)                                                 \
    (*(const float4*)((SRC) + ((tid + (K) * 256) / 25) * 7500 +         \
                      ((tid + (K) * 256) % 25) * 4))
#define B_STEP(TL2)                                                     \
    {                                                                   \
        int kb_ = (TL2) * 2 + hi;                                       \
        short8 af_ = *(const short8*)&abT[(w * 32 + v32) * 64 +         \
                                          (((kb_ + v32) & 7) << 3)];    \
        short8 bf_ = *(const short8*)&abT[((3 + w) * 32 + v32) * 64 +   \
                                          (((kb_ + v32) & 7) << 3)];    \
        accB = __builtin_amdgcn_mfma_f32_32x32x16_bf16(af_, bf_, accB,  \
                                                       0, 0, 0);        \
    }

    // ---- St(0)
    {
        const float* xs0 = xb0;
        #pragma unroll
        for (int k = 0; k < 7; ++k) {
            if (k < 6 || tid < 64) {
                float4 pv0 = ST_LOAD(xs0, k);
                ST_LOADW(pv0, k)
            }
        }
    }
    __syncthreads();

    for (int s = 0; s < 3; ++s) {
        // ---- phase A(s): ab = W @ x on 32x32x16; 3 rt tiles, ct = w
        #pragma unroll
        for (int rt = 0; rt < 3; ++rt) {
            f32x16 d;
            #pragma unroll
            for (int r = 0; r < 16; ++r) d[r] = 0.f;
            #pragma unroll
            for (int k16 = 0; k16 < 4; ++k16) {
                int kb = k16 * 2 + hi;
                short8 af = *(const short8*)(wb2 + (kb * 96 + rt * 32 + v32) * 8);
                short8 bf = *(const short8*)&xT[tv * 64 +
                                                (((kb + tv + (tv >> 2)) & 7) << 3)];
                d = __builtin_amdgcn_mfma_f32_32x32x16_bf16(af, bf, d, 0, 0, 0);
            }
            if (avalid) {
                #pragma unroll
                for (int a = 0; a < 4; ++a) {
                    int rowoff = 8 * a + 4 * hi;            // D row within 32
                    int g   = rt * 2 + (rowoff >> 4);       // abT group
                    int icb = rowoff & 15;
                    float4 bq = *(const float4*)(
                        (const float*)(abT + (31 + rt * 32) * 64) + rowoff);
                    int kbw = tl * 2 + (icb >> 3);
                    uint32* dst = (uint32*)&abT[(g * 32 + vv) * 64 +
                                                (((kbw + vv) & 7) << 3) + (icb & 7)];
                    dst[0] = packbf2(d[4 * a + 0] + bq.x, d[4 * a + 1] + bq.y);
                    dst[1] = packbf2(d[4 * a + 2] + bq.z, d[4 * a + 3] + bq.w);
                }
            }
        }
        __syncthreads();   // A(s) done: xT free to overwrite, abT(s) ready

        if (s < 2) {
            // ---- merged region: St(s+1) || B(s), split in halves to cap
            // in-flight float4 at 4 (peak VGPR ~50 < 64; round-5/6 lesson)
            const float* xsN = xb0 + (s + 1) * 100;
            {
                float4 p0 = ST_LOAD(xsN, 0);
                float4 p1 = ST_LOAD(xsN, 1);
                float4 p2 = ST_LOAD(xsN, 2);
                float4 p3 = ST_LOAD(xsN, 3);
                if (w < 3) { B_STEP(0) B_STEP(1) }
                ST_LOADW(p0, 0)
                ST_LOADW(p1, 1)
                ST_LOADW(p2, 2)
                ST_LOADW(p3, 3)
            }
            {
                float4 p4 = ST_LOAD(xsN, 4);
                float4 p5 = ST_LOAD(xsN, 5);
                float4 p6;
                if (tid < 64) p6 = ST_LOAD(xsN, 6);
                if (w < 3) { B_STEP(2) B_STEP(3) }
                ST_LOADW(p4, 4)
                ST_LOADW(p5, 5)
                if (tid < 64) ST_LOADW(p6, 6)
            }
            __syncthreads();   // xT(s+1) staged, B(s) done with abT(s)
        } else {
            // ---- B(2): no staging left, no trailing barrier needed
            if (w < 3) { B_STEP(0) B_STEP(1) B_STEP(2) B_STEP(3) }
        }
    }

    // ---- tail: plain stores of the partial M_i into this block's
    // private slice Mp[i][n][chunk][640] (no contention, no atomics)
    if (w < 3 && v32 < 25) {
        const float inv = 1.0f / 4800.0f;
        float* dst = Mp + ((w * NB + n) * 25 + chunk) * 640;
        #pragma unroll
        for (int r = 0; r < 16; ++r) {
            int row = (r & 3) + 8 * (r >> 2) + 4 * hi;   // m74/m101 C-layout
            if (row < 25)
                dst[row * 25 + v32] = accB[r] * inv;
        }
    }
#undef ST_LOADW
#undef ST_LOAD
#undef B_STEP
}

// ---------------------------------------------------------------- kernel 2
// 192 blocks = (i,n) x 256 thr; float4 chunk-sum (Mp rows 640-padded,
// 16B-aligned), then softmax over v1 + A_tot -> atT bf16.
__global__ __launch_bounds__(256) void k2_softmax(
    const float* __restrict__ Mp, const float* __restrict__ A,
    const float* __restrict__ GA, uint32* __restrict__ atT)
{
    __shared__ __align__(16) float Ms[640];
    const int b   = blockIdx.x;
    const int tid = threadIdx.x;
    const int i = b >> 6, n = b & 63;
    const float* src = Mp + (size_t)b * 25 * 640;   // [i][n] slice
    if (tid < 156) {
        float4 a4 = make_float4(0.f, 0.f, 0.f, 0.f);
        #pragma unroll 5
        for (int ch = 0; ch < 25; ++ch) {
            float4 v = *(const float4*)(src + ch * 640 + tid * 4);
            a4.x += v.x; a4.y += v.y; a4.z += v.z; a4.w += v.w;
        }
        *(float4*)(Ms + tid * 4) = a4;
    } else if (tid == 156) {
        float ssum = 0.f;
        #pragma unroll 5
        for (int ch = 0; ch < 25; ++ch) ssum += src[ch * 640 + 624];
        Ms[624] = ssum;
    }
    __syncthreads();
    if (tid < 25) {
        const int v2 = tid;
        float e[25], mx = -1e30f;
        #pragma unroll
        for (int v1 = 0; v1 < 25; ++v1) {
            e[v1] = Ms[v1 * 25 + v2];
            mx = fmaxf(mx, e[v1]);
        }
        float s = 0.f;
        #pragma unroll
        for (int v1 = 0; v1 < 25; ++v1) { e[v1] = __expf(e[v1] - mx); s += e[v1]; }
        float invs = 1.0f / s;
        const float* acol = A + i * 625 + v2;
        const float* gcol = GA + i * 625 + v2;
        float wv[25];
        #pragma unroll
        for (int v1 = 0; v1 < 25; ++v1)
            wv[v1] = e[v1] * invs + acol[v1 * 25] + gcol[v1 * 25];
        uint32* row = atT + ((i * 64 + n) * 32 + v2) * 16;
        #pragma unroll
        for (int p = 0; p < 12; ++p) row[p] = packbf2(wv[2 * p], wv[2 * p + 1]);
        row[12] = (uint32)f2bf(wv[24]);
        row[13] = 0u; row[14] = 0u; row[15] = 0u;
    }
}

// ---------------------------------------------------------------- kernel 3
// Stage-less MFMA. grid 3840 = 64 n * 60 chunks of 5 t; 256 thr = 4 waves.
// LDS: xa 18432 + bsc/bsh 512 = 18944 B.
__global__ __launch_bounds__(256) void k3_out(
    const float* __restrict__ x, const uint32* __restrict__ atT,
    const ushort16* __restrict__ gwb, const float* __restrict__ g_b,
    const float* __restrict__ bn_g, const float* __restrict__ bn_b,
    const float* __restrict__ bn_m, const float* __restrict__ bn_v,
    float* __restrict__ out)
{
    __shared__ uint32 xa[128 * 36];     // [col=(t,v2) pad128][c: 72 bf16 as 36 u32]
    __shared__ float  bsc[64], bsh[64];

    const int tid = threadIdx.x;
    const int n  = blockIdx.x / 60;
    const int t0 = (blockIdx.x % 60) * 5;

    // BN scale/shift prefold (h = acc*sc + sh + x)
    if (tid < 64) {
        float sc = bn_g[tid] * rsqrtf(bn_v[tid] + 1e-5f);
        bsc[tid] = sc;
        bsh[tid] = (g_b[tid] + g_b[64 + tid] + g_b[128 + tid] - bn_m[tid]) * sc
                   + bn_b[tid];
    }
    // zero xa pad rows (cols 125..127)
    for (int idx = tid; idx < 108; idx += 256)
        xa[(125 + idx / 36) * 36 + idx % 36] = 0u;

    const int w    = tid >> 6;      // wave id = o-tile (main) = c-tile (xa)
    const int lane = tid & 63;
    const int l15  = lane & 15;
    const int q    = lane >> 4;

    // preload A-frags of gw (all 6 K-steps: k = i*64 + s*32)
    short8 gf[6];
    #pragma unroll
    for (int s = 0; s < 6; ++s)
        gf[s] = *(const short8*)(gwb + ((w * 16 + l15) * 192 + s * 32 + q * 8));

    // A-frags of x direct from global: lane (q,l15) of wave w holds
    // c = w*16+l15, k = v1 in [q*8, q*8+8). v1 >= 25 reads the next t-row
    // (garbage but finite, in-bounds via clamp) and meets B's zero pad.
    const int c    = w * 16 + l15;
    const int rowf = (n * 64 + c) * 7500 + t0 * 25;
    short8 axf[5];
    #pragma unroll
    for (int t = 0; t < 5; ++t) {
        int fi = rowf + t * 25 + q * 8;
        fi = fi < (XTOT - 8) ? fi : (XTOT - 8);
        const float* p = x + fi;
        union { short8 s; uint32 u[4]; } fr;
        fr.u[0] = packbf2(p[0], p[1]);
        fr.u[1] = packbf2(p[2], p[3]);
        fr.u[2] = packbf2(p[4], p[5]);
        fr.u[3] = packbf2(p[6], p[7]);
        axf[t] = fr.s;
    }

    f32x4 acc[8];
    #pragma unroll
    for (int ct = 0; ct < 8; ++ct) acc[ct] = (f32x4){0.f, 0.f, 0.f, 0.f};
    const f32x4 zf = (f32x4){0.f, 0.f, 0.f, 0.f};

    __syncthreads();

    for (int i = 0; i < 3; ++i) {
        if (i) __syncthreads();   // previous xa fully consumed
        // B-frags for this i straight from global atT (16B-aligned, L2-hot)
        const ushort16* ap = (const ushort16*)atT + ((i * 64 + n) * 32) * 32;
        short8 bt0 = *(const short8*)(ap + l15 * 32 + q * 8);
        short8 bt1 = *(const short8*)(ap + (16 + l15) * 32 + q * 8);
        // ---- xa-phase: this wave produces c-rows [w*16, w*16+16)
        #pragma unroll
        for (int t = 0; t < 5; ++t) {
            #pragma unroll
            for (int vt = 0; vt < 2; ++vt) {
                f32x4 d = __builtin_amdgcn_mfma_f32_16x16x32_bf16(
                    axf[t], vt ? bt1 : bt0, zf, 0, 0, 0);
                int v2 = vt * 16 + l15;
                if (v2 < 25) {
                    int col = t * 25 + v2;
                    int c0  = w * 16 + q * 4;
                    xa[col * 36 + (c0 >> 1)]     = packbf2(d[0], d[1]);
                    xa[col * 36 + (c0 >> 1) + 1] = packbf2(d[2], d[3]);
                }
            }
        }
        __syncthreads();
        // ---- main GEMM: acc[o,col] += gw_i[o,c] * xa[c,col]
        #pragma unroll
        for (int ct = 0; ct < 8; ++ct) {
            #pragma unroll
            for (int s = 0; s < 2; ++s) {
                short8 bfrag = *(const short8*)((const ushort16*)xa +
                                                (ct * 16 + l15) * 72 + s * 32 + q * 8);
                acc[ct] = __builtin_amdgcn_mfma_f32_16x16x32_bf16(
                    gf[i * 2 + s], bfrag, acc[ct], 0, 0, 0);
            }
        }
    }

    // ---- epilogue: BN + residual (f32 x from global, same offsets as out)
    const int o0 = w * 16 + q * 4;
    #pragma unroll
    for (int ct = 0; ct < 8; ++ct) {
        int col = ct * 16 + l15;
        if (col < 125) {
            int off = (n * 64 + o0) * 7500 + t0 * 25 + col;
            float* ob = out + off;
            const float* xb = x + off;
            #pragma unroll
            for (int r = 0; r < 4; ++r) {
                float h = acc[ct][r] * bsc[o0 + r] + bsh[o0 + r] + xb[r * 7500];
                ob[r * 7500] = fmaxf(h, 0.f);
            }
        }
    }
}

// ---------------------------------------------------------------- launch
extern "C" void kernel_launch(void* const* d_in, const int* in_sizes, int n_in,
                              void* d_out, int out_size, void* d_ws, size_t ws_size,
                              hipStream_t stream) {
    const float* x    = (const float*)d_in[0];
    const float* A    = (const float*)d_in[1];
    const float* GA   = (const float*)d_in[2];
    const float* g_w  = (const float*)d_in[3];
    const float* g_b  = (const float*)d_in[4];
    const float* a_w  = (const float*)d_in[5];
    const float* a_b  = (const float*)d_in[6];
    const float* b_w  = (const float*)d_in[7];
    const float* b_b  = (const float*)d_in[8];
    const float* bn_g = (const float*)d_in[9];
    const float* bn_b = (const float*)d_in[10];
    const float* bn_m = (const float*)d_in[11];
    const float* bn_v = (const float*)d_in[12];
    float* out = (float*)d_out;

    // ws: Mp f32 [3][64][25][640] (12,288,000 B) | atT bf16 (393,216 B)
    //     | gwb (24,576 B). wb2 (12,288 B) OVERLAPS the start of atT:
    // k0 writes wb2 -> k1 reads wb2 -> k2 overwrites region with atT ->
    // k3 reads atT. Stream-serial. No memset needed (Mp fully overwritten).
    float*    Mp  = (float*)d_ws;
    uint32*   atT = (uint32*)((char*)d_ws + 12288000);
    ushort16* wb2 = (ushort16*)((char*)d_ws + 12288000);
    uint32*   gwb = (uint32*)((char*)d_ws + 12288000 + 393216);

    k0_prep<<<dim3(48), dim3(256), 0, stream>>>(a_w, b_w, g_w, wb2, gwb);
    k1_attn_logits_mfma<<<dim3(1600), dim3(256), 0, stream>>>(x, wb2, a_b, b_b, Mp);
    k2_softmax<<<dim3(192), dim3(256), 0, stream>>>(Mp, A, GA, atT);
    k3_out<<<dim3(3840), dim3(256), 0, stream>>>(x, atT, (const ushort16*)gwb,
                                                 g_b, bn_g, bn_b, bn_m, bn_v, out);
}

// Round 11
// 324.403 us; speedup vs baseline: 1.0718x; 1.0093x over previous
//
#include <hip/hip_runtime.h>
#include <hip/hip_bf16.h>

// AdaptiveGraphConvolution on MI355X — round 13 (= round-12 resubmit;
// round-10 bench was an infra failure "container failed twice", no
// counters — same signature as round 1 which passed on resubmit).
// N=64, C=64, T=300, V=25, S=3 subsets, IC=16, O=64.
//
// Round-12 design (k1 rewrite, stage-less):
//  * xT buffer + staging phase DELETED. Phase-A B-frags load DIRECTLY
//    from global x: lane at col tv reads 8 consecutive c (stride 7500);
//    across a half-wave tv is contiguous -> each scalar load instr is a
//    coalesced 128 B segment. Same bytes as staging, no LDS round-trip,
//    no cvt staging pass, element order identical to the old xT path.
//  * LDS 40704 -> 24576 B (abT only) = 6 blocks/CU (was 4): 24 waves/CU
//    TLP hides the in-phase load latency.
//  * Barriers: 1 (bias stash) + 2/s = 7, no St convoy.
//  * Live VGPR ~60 <= 64 (bfr 16 + accB 16 + d 16 + misc): no spill
//    expected; tripwire = FETCH >> 66 MB.
//  * Bounds audit: max read = chunk*300 + s*100 + tvc + 63*7500
//    = 7200+200+99+472500 = 479,999 < 480,000 floats per n-slice.
// k0/k2/k3 unchanged from round 11 (passing, 327.4 us).
// Workspace: Mp 12,288,000 B | atT 393,216 B | gwb 24,576 B.

#define NB 64
#define CB 64
#define TB 300
#define VB 25
#define XTOT (NB * CB * TB * VB)

typedef unsigned int uint32;
typedef unsigned short ushort16;
typedef __attribute__((ext_vector_type(8))) short short8;
typedef __attribute__((ext_vector_type(4))) float f32x4;
typedef __attribute__((ext_vector_type(16))) float f32x16;

__device__ __forceinline__ ushort16 f2bf(float f) {
    __hip_bfloat16 h = __float2bfloat16(f);
    ushort16 u;
    __builtin_memcpy(&u, &h, sizeof(u));
    return u;
}
__device__ __forceinline__ float bf2f(ushort16 h) {
    return __uint_as_float(((uint32)h) << 16);
}
__device__ __forceinline__ uint32 packbf2(float a, float b) {
    return (uint32)f2bf(a) | ((uint32)f2bf(b) << 16);
}

// ---------------------------------------------------------------- kernel 0
// one-time weight prep. grid 48 x 256.
//   idx <  6144: W bf16, layout [kb8][r][8]
//   idx < 12288: g_w -> gwb bf16 pairs (k3 A-operand layout)
__global__ __launch_bounds__(256) void k0_prep(
    const float* __restrict__ a_w, const float* __restrict__ b_w,
    const float* __restrict__ g_w,
    ushort16* __restrict__ wb2, uint32* __restrict__ gwb)
{
    int idx = blockIdx.x * 256 + threadIdx.x;
    if (idx < 6144) {
        int kb = idx / 768, rem = idx % 768;
        int r = rem >> 3, ci = rem & 7;
        int c = kb * 8 + ci;
        float v = (r < 48) ? a_w[r * 64 + c] : b_w[(r - 48) * 64 + c];
        wb2[idx] = f2bf(v);
    } else if (idx < 12288) {
        int j = idx - 6144;
        int o = j / 96, kp = j % 96;
        int k0 = 2 * kp, i = k0 >> 6, c = k0 & 63;
        float2 lh = *(const float2*)(g_w + (i * 64 + o) * 64 + c);
        gwb[j] = packbf2(lh.x, lh.y);
    }
}

// ---------------------------------------------------------------- kernel 1
// grid 1600 = 64 n * 25 chunks (12 t), 256 thr = 4 waves, 6 blocks/CU.
// Per s: [4 B-frags direct from global; A: 3rt x 4k MFMA -> abT; bar;
// B: 4 MFMA (w<3); bar]. No staging phase, no xT.
__global__ __launch_bounds__(256) void k1_attn_logits_mfma(
    const float* __restrict__ x, const ushort16* __restrict__ wb2,
    const float* __restrict__ a_b, const float* __restrict__ b_b,
    float* __restrict__ Mp)
{
    __shared__ ushort16 abT[192 * 64];   // 24576 B -> 6 blocks/CU

    const int tid   = threadIdx.x;
    const int n     = blockIdx.x / 25;
    const int chunk = blockIdx.x % 25;
    const float* xn = x + n * (CB * TB * VB);

    // bias stash: f32 in abT rows 31/63/95 (phase-B reads of rows v>=25
    // produce discarded outputs; phase-A writes only touch v<25).
    if (tid < 96) {
        float v = (tid < 48) ? a_b[tid] : b_b[tid - 48];
        ((float*)(abT + (31 + (tid >> 5) * 32) * 64))[tid & 31] = v;
    }

    const int w    = tid >> 6;
    const int lane = tid & 63;
    const int hi   = lane >> 5;
    const int v32  = lane & 31;

    // wave w owns col-tile ct=w: col tv = w*32 + v32 (valid iff < 100)
    const int tv      = w * 32 + v32;
    const bool avalid = tv < 100;
    const int tvc = avalid ? tv : 99;        // clamped col for loads
    const int tl  = tv / 25;                 // used only when avalid
    const int vv  = tv - tl * 25;

    // per-lane global column base: x[n][c=0][chunk*12 + ...][tvc]
    const float* xcol = xn + chunk * 300 + tvc;

    f32x16 accB;
    #pragma unroll
    for (int r = 0; r < 16; ++r) accB[r] = 0.f;

    __syncthreads();   // bias stash visible to phase-A bq reads

    for (int s = 0; s < 3; ++s) {
        // ---- B-frags direct from global: bfr[k16] = cols (kb*8..+8, tv),
        // kb = k16*2 + hi. Element j of short8 = c = kb*8 + j (same order
        // as the old xT path). Lanes of a half-wave have consecutive tv ->
        // each scalar load instruction covers a contiguous 128 B segment.
        const float* xs = xcol + s * 100;
        short8 bfr[4];
        #pragma unroll
        for (int k16 = 0; k16 < 4; ++k16) {
            const float* p = xs + (k16 * 2 + hi) * 8 * 7500;
            union { short8 s8; uint32 u[4]; } fr;
            fr.u[0] = packbf2(p[0],     p[7500]);
            fr.u[1] = packbf2(p[15000], p[22500]);
            fr.u[2] = packbf2(p[30000], p[37500]);
            fr.u[3] = packbf2(p[45000], p[52500]);
            bfr[k16] = fr.s8;
        }
        // ---- phase A: ab = W @ x on 32x32x16; 3 rt tiles, ct = w
        #pragma unroll
        for (int rt = 0; rt < 3; ++rt) {
            f32x16 d;
            #pragma unroll
            for (int r = 0; r < 16; ++r) d[r] = 0.f;
            #pragma unroll
            for (int k16 = 0; k16 < 4; ++k16) {
                int kb = k16 * 2 + hi;
                short8 af = *(const short8*)(wb2 + (kb * 96 + rt * 32 + v32) * 8);
                d = __builtin_amdgcn_mfma_f32_32x32x16_bf16(af, bfr[k16], d, 0, 0, 0);
            }
            if (avalid) {
                #pragma unroll
                for (int a = 0; a < 4; ++a) {
                    int rowoff = 8 * a + 4 * hi;            // D row within 32
                    int g   = rt * 2 + (rowoff >> 4);       // abT group
                    int icb = rowoff & 15;
                    float4 bq = *(const float4*)(
                        (const float*)(abT + (31 + rt * 32) * 64) + rowoff);
                    int kbw = tl * 2 + (icb >> 3);
                    uint32* dst = (uint32*)&abT[(g * 32 + vv) * 64 +
                                                (((kbw + vv) & 7) << 3) + (icb & 7)];
                    dst[0] = packbf2(d[4 * a + 0] + bq.x, d[4 * a + 1] + bq.y);
                    dst[1] = packbf2(d[4 * a + 2] + bq.z, d[4 * a + 3] + bq.w);
                }
            }
        }
        __syncthreads();   // abT(s) ready for phase B
        // ---- phase B: wave w (<3) owns subset i=w, all 4 local t
        if (w < 3) {
            #pragma unroll
            for (int tl2 = 0; tl2 < 4; ++tl2) {
                int kb = tl2 * 2 + hi;
                short8 af = *(const short8*)&abT[(w * 32 + v32) * 64 +
                                                 (((kb + v32) & 7) << 3)];
                short8 bf = *(const short8*)&abT[((3 + w) * 32 + v32) * 64 +
                                                 (((kb + v32) & 7) << 3)];
                accB = __builtin_amdgcn_mfma_f32_32x32x16_bf16(af, bf, accB, 0, 0, 0);
            }
        }
        __syncthreads();   // B(s) done with abT before A(s+1) overwrites
    }

    // ---- tail: plain stores of the partial M_i into this block's
    // private slice Mp[i][n][chunk][640] (no contention, no atomics)
    if (w < 3 && v32 < 25) {
        const float inv = 1.0f / 4800.0f;
        float* dst = Mp + ((w * NB + n) * 25 + chunk) * 640;
        #pragma unroll
        for (int r = 0; r < 16; ++r) {
            int row = (r & 3) + 8 * (r >> 2) + 4 * hi;   // m74/m101 C-layout
            if (row < 25)
                dst[row * 25 + v32] = accB[r] * inv;
        }
    }
}

// ---------------------------------------------------------------- kernel 2
// 192 blocks = (i,n) x 256 thr; float4 chunk-sum (Mp rows 640-padded,
// 16B-aligned), then softmax over v1 + A_tot -> atT bf16.
__global__ __launch_bounds__(256) void k2_softmax(
    const float* __restrict__ Mp, const float* __restrict__ A,
    const float* __restrict__ GA, uint32* __restrict__ atT)
{
    __shared__ __align__(16) float Ms[640];
    const int b   = blockIdx.x;
    const int tid = threadIdx.x;
    const int i = b >> 6, n = b & 63;
    const float* src = Mp + (size_t)b * 25 * 640;   // [i][n] slice
    if (tid < 156) {
        float4 a4 = make_float4(0.f, 0.f, 0.f, 0.f);
        #pragma unroll 5
        for (int ch = 0; ch < 25; ++ch) {
            float4 v = *(const float4*)(src + ch * 640 + tid * 4);
            a4.x += v.x; a4.y += v.y; a4.z += v.z; a4.w += v.w;
        }
        *(float4*)(Ms + tid * 4) = a4;
    } else if (tid == 156) {
        float ssum = 0.f;
        #pragma unroll 5
        for (int ch = 0; ch < 25; ++ch) ssum += src[ch * 640 + 624];
        Ms[624] = ssum;
    }
    __syncthreads();
    if (tid < 25) {
        const int v2 = tid;
        float e[25], mx = -1e30f;
        #pragma unroll
        for (int v1 = 0; v1 < 25; ++v1) {
            e[v1] = Ms[v1 * 25 + v2];
            mx = fmaxf(mx, e[v1]);
        }
        float s = 0.f;
        #pragma unroll
        for (int v1 = 0; v1 < 25; ++v1) { e[v1] = __expf(e[v1] - mx); s += e[v1]; }
        float invs = 1.0f / s;
        const float* acol = A + i * 625 + v2;
        const float* gcol = GA + i * 625 + v2;
        float wv[25];
        #pragma unroll
        for (int v1 = 0; v1 < 25; ++v1)
            wv[v1] = e[v1] * invs + acol[v1 * 25] + gcol[v1 * 25];
        uint32* row = atT + ((i * 64 + n) * 32 + v2) * 16;
        #pragma unroll
        for (int p = 0; p < 12; ++p) row[p] = packbf2(wv[2 * p], wv[2 * p + 1]);
        row[12] = (uint32)f2bf(wv[24]);
        row[13] = 0u; row[14] = 0u; row[15] = 0u;
    }
}

// ---------------------------------------------------------------- kernel 3
// Stage-less MFMA. grid 3840 = 64 n * 60 chunks of 5 t; 256 thr = 4 waves.
// LDS: xa 18432 + bsc/bsh 512 = 18944 B.
__global__ __launch_bounds__(256) void k3_out(
    const float* __restrict__ x, const uint32* __restrict__ atT,
    const ushort16* __restrict__ gwb, const float* __restrict__ g_b,
    const float* __restrict__ bn_g, const float* __restrict__ bn_b,
    const float* __restrict__ bn_m, const float* __restrict__ bn_v,
    float* __restrict__ out)
{
    __shared__ uint32 xa[128 * 36];     // [col=(t,v2) pad128][c: 72 bf16 as 36 u32]
    __shared__ float  bsc[64], bsh[64];

    const int tid = threadIdx.x;
    const int n  = blockIdx.x / 60;
    const int t0 = (blockIdx.x % 60) * 5;

    // BN scale/shift prefold (h = acc*sc + sh + x)
    if (tid < 64) {
        float sc = bn_g[tid] * rsqrtf(bn_v[tid] + 1e-5f);
        bsc[tid] = sc;
        bsh[tid] = (g_b[tid] + g_b[64 + tid] + g_b[128 + tid] - bn_m[tid]) * sc
                   + bn_b[tid];
    }
    // zero xa pad rows (cols 125..127)
    for (int idx = tid; idx < 108; idx += 256)
        xa[(125 + idx / 36) * 36 + idx % 36] = 0u;

    const int w    = tid >> 6;      // wave id = o-tile (main) = c-tile (xa)
    const int lane = tid & 63;
    const int l15  = lane & 15;
    const int q    = lane >> 4;

    // preload A-frags of gw (all 6 K-steps: k = i*64 + s*32)
    short8 gf[6];
    #pragma unroll
    for (int s = 0; s < 6; ++s)
        gf[s] = *(const short8*)(gwb + ((w * 16 + l15) * 192 + s * 32 + q * 8));

    // A-frags of x direct from global: lane (q,l15) of wave w holds
    // c = w*16+l15, k = v1 in [q*8, q*8+8). v1 >= 25 reads the next t-row
    // (garbage but finite, in-bounds via clamp) and meets B's zero pad.
    const int c    = w * 16 + l15;
    const int rowf = (n * 64 + c) * 7500 + t0 * 25;
    short8 axf[5];
    #pragma unroll
    for (int t = 0; t < 5; ++t) {
        int fi = rowf + t * 25 + q * 8;
        fi = fi < (XTOT - 8) ? fi : (XTOT - 8);
        const float* p = x + fi;
        union { short8 s; uint32 u[4]; } fr;
        fr.u[0] = packbf2(p[0], p[1]);
        fr.u[1] = packbf2(p[2], p[3]);
        fr.u[2] = packbf2(p[4], p[5]);
        fr.u[3] = packbf2(p[6], p[7]);
        axf[t] = fr.s;
    }

    f32x4 acc[8];
    #pragma unroll
    for (int ct = 0; ct < 8; ++ct) acc[ct] = (f32x4){0.f, 0.f, 0.f, 0.f};
    const f32x4 zf = (f32x4){0.f, 0.f, 0.f, 0.f};

    __syncthreads();

    for (int i = 0; i < 3; ++i) {
        if (i) __syncthreads();   // previous xa fully consumed
        // B-frags for this i straight from global atT (16B-aligned, L2-hot)
        const ushort16* ap = (const ushort16*)atT + ((i * 64 + n) * 32) * 32;
        short8 bt0 = *(const short8*)(ap + l15 * 32 + q * 8);
        short8 bt1 = *(const short8*)(ap + (16 + l15) * 32 + q * 8);
        // ---- xa-phase: this wave produces c-rows [w*16, w*16+16)
        #pragma unroll
        for (int t = 0; t < 5; ++t) {
            #pragma unroll
            for (int vt = 0; vt < 2; ++vt) {
                f32x4 d = __builtin_amdgcn_mfma_f32_16x16x32_bf16(
                    axf[t], vt ? bt1 : bt0, zf, 0, 0, 0);
                int v2 = vt * 16 + l15;
                if (v2 < 25) {
                    int col = t * 25 + v2;
                    int c0  = w * 16 + q * 4;
                    xa[col * 36 + (c0 >> 1)]     = packbf2(d[0], d[1]);
                    xa[col * 36 + (c0 >> 1) + 1] = packbf2(d[2], d[3]);
                }
            }
        }
        __syncthreads();
        // ---- main GEMM: acc[o,col] += gw_i[o,c] * xa[c,col]
        #pragma unroll
        for (int ct = 0; ct < 8; ++ct) {
            #pragma unroll
            for (int s = 0; s < 2; ++s) {
                short8 bfrag = *(const short8*)((const ushort16*)xa +
                                                (ct * 16 + l15) * 72 + s * 32 + q * 8);
                acc[ct] = __builtin_amdgcn_mfma_f32_16x16x32_bf16(
                    gf[i * 2 + s], bfrag, acc[ct], 0, 0, 0);
            }
        }
    }

    // ---- epilogue: BN + residual (f32 x from global, same offsets as out)
    const int o0 = w * 16 + q * 4;
    #pragma unroll
    for (int ct = 0; ct < 8; ++ct) {
        int col = ct * 16 + l15;
        if (col < 125) {
            int off = (n * 64 + o0) * 7500 + t0 * 25 + col;
            float* ob = out + off;
            const float* xb = x + off;
            #pragma unroll
            for (int r = 0; r < 4; ++r) {
                float h = acc[ct][r] * bsc[o0 + r] + bsh[o0 + r] + xb[r * 7500];
                ob[r * 7500] = fmaxf(h, 0.f);
            }
        }
    }
}

// ---------------------------------------------------------------- launch
extern "C" void kernel_launch(void* const* d_in, const int* in_sizes, int n_in,
                              void* d_out, int out_size, void* d_ws, size_t ws_size,
                              hipStream_t stream) {
    const float* x    = (const float*)d_in[0];
    const float* A    = (const float*)d_in[1];
    const float* GA   = (const float*)d_in[2];
    const float* g_w  = (const float*)d_in[3];
    const float* g_b  = (const float*)d_in[4];
    const float* a_w  = (const float*)d_in[5];
    const float* a_b  = (const float*)d_in[6];
    const float* b_w  = (const float*)d_in[7];
    const float* b_b  = (const float*)d_in[8];
    const float* bn_g = (const float*)d_in[9];
    const float* bn_b = (const float*)d_in[10];
    const float* bn_m = (const float*)d_in[11];
    const float* bn_v = (const float*)d_in[12];
    float* out = (float*)d_out;

    // ws: Mp f32 [3][64][25][640] (12,288,000 B) | atT bf16 (393,216 B)
    //     | gwb (24,576 B). wb2 (12,288 B) OVERLAPS the start of atT:
    // k0 writes wb2 -> k1 reads wb2 -> k2 overwrites region with atT ->
    // k3 reads atT. Stream-serial. No memset needed (Mp fully overwritten).
    float*    Mp  = (float*)d_ws;
    uint32*   atT = (uint32*)((char*)d_ws + 12288000);
    ushort16* wb2 = (ushort16*)((char*)d_ws + 12288000);
    uint32*   gwb = (uint32*)((char*)d_ws + 12288000 + 393216);

    k0_prep<<<dim3(48), dim3(256), 0, stream>>>(a_w, b_w, g_w, wb2, gwb);
    k1_attn_logits_mfma<<<dim3(1600), dim3(256), 0, stream>>>(x, wb2, a_b, b_b, Mp);
    k2_softmax<<<dim3(192), dim3(256), 0, stream>>>(Mp, A, GA, atT);
    k3_out<<<dim3(3840), dim3(256), 0, stream>>>(x, atT, (const ushort16*)gwb,
                                                 g_b, bn_g, bn_b, bn_m, bn_v, out);
}